// Round 7
// baseline (305.698 us; speedup 1.0000x reference)
//
#include <hip/hip_runtime.h>

typedef unsigned short u16;
typedef __attribute__((ext_vector_type(8))) short bf16x8;
typedef __attribute__((ext_vector_type(4))) float f32x4;

#define BATCH 4
#define SEQ   2048
#define DM    1024
#define HEADS 16
#define FEAT  16
#define HD    64
#define EXPD  273
#define EXPP  288   // padded to multiple of 32 for MFMA K
#define CHK   128
#define NC    16    // SEQ / CHK
#define BH    64    // BATCH*HEADS
#define QKS   512   // fused QK projection row stride
#define MROWS 8192  // BATCH*SEQ
#define C2    0.17677669529663687f  // 1/(sqrt(2)*sqrt(16))

__device__ __forceinline__ u16 f2b(float f) {
  union { float f; unsigned u; } v; v.f = f;
  unsigned u = v.u;
  return (u16)((u + 0x7fffu + ((u >> 16) & 1u)) >> 16);
}
__device__ __forceinline__ float b2f(u16 s) {
  union { unsigned u; float f; } v; v.u = ((unsigned)s) << 16; return v.f;
}

typedef const unsigned int __attribute__((address_space(1)))* gas1;
typedef unsigned int __attribute__((address_space(3)))* las3;
__device__ __forceinline__ void gl_lds16(const u16* g, u16* l) {
  __builtin_amdgcn_global_load_lds((gas1)(const void*)g, (las3)(void*)l, 16, 0, 0);
}

// Fused prep: x->bf16 (blocks 0..8191), 4 weight cast-transposes (8192..10751), bias concat (10752)
__global__ __launch_bounds__(256) void prep(const float* __restrict__ x, u16* __restrict__ xb,
                                            const float* __restrict__ Wq, const float* __restrict__ Wk,
                                            const float* __restrict__ Wv, const float* __restrict__ Wo,
                                            u16* __restrict__ wqkT, u16* __restrict__ wvT, u16* __restrict__ woT,
                                            const float* __restrict__ bq, const float* __restrict__ bk,
                                            float* __restrict__ bqk) {
  __shared__ float tile[32][33];
  int id = blockIdx.x;
  if (id < 8192) {
    int i = id * 256 + threadIdx.x;
    float4 v = ((const float4*)x)[i];
    u16 r[4] = {f2b(v.x), f2b(v.y), f2b(v.z), f2b(v.w)};
    ((uint2*)xb)[i] = *(uint2*)r;
    return;
  }
  id -= 8192;
  if (id < 2560) {
    const float* src; u16* dst; int N, t;
    if (id < 256)       { src = Wq; dst = wqkT;            N = 256;  t = id; }
    else if (id < 512)  { src = Wk; dst = wqkT + 256 * DM; N = 256;  t = id - 256; }
    else if (id < 1536) { src = Wv; dst = wvT;             N = 1024; t = id - 512; }
    else                { src = Wo; dst = woT;             N = 1024; t = id - 1536; }
    int nt = N / 32;
    int n0 = (t % nt) * 32, k0 = (t / nt) * 32;
    int tx = threadIdx.x & 31, ty = threadIdx.x >> 5;
    for (int i = ty; i < 32; i += 8)
      tile[i][tx] = src[(size_t)(k0 + i) * N + n0 + tx];
    __syncthreads();
    for (int i = ty; i < 32; i += 8)
      dst[(size_t)(n0 + i) * DM + k0 + tx] = f2b(tile[tx][i]);
    return;
  }
  int i = threadIdx.x;
  bqk[i] = bq[i];
  bqk[256 + i] = bk[i];
}

// C = A(MxK bf16 rm) @ BT^T + bias.  BT is [N][K] bf16 row-major.
__global__ __launch_bounds__(256) void gemm128(const u16* __restrict__ A, const u16* __restrict__ BT,
                                               const float* __restrict__ bias, int M, int N, int K,
                                               float* __restrict__ outF, u16* __restrict__ outB,
                                               u16* __restrict__ outT) {
  __shared__ __align__(16) u16 As[128 * 32];
  __shared__ __align__(16) u16 Bs[128 * 32];
  const int tid = threadIdx.x;
  const int wave = tid >> 6, lane = tid & 63, qd = lane >> 4, ln = lane & 15;
  const int wr = (wave >> 1) * 64, wc = (wave & 1) * 64;
  const int m0 = blockIdx.y * 128, n0 = blockIdx.x * 128;
  f32x4 acc[4][4];
#pragma unroll
  for (int i = 0; i < 4; i++)
#pragma unroll
    for (int j = 0; j < 4; j++) acc[i][j] = (f32x4){0.f, 0.f, 0.f, 0.f};
  const int sr = tid >> 2, sk = (tid & 3) * 8;
  const u16* gA0 = A + (size_t)(m0 + sr) * K + sk;
  const u16* gA1 = A + (size_t)(m0 + 64 + sr) * K + sk;
  const u16* gB0 = BT + (size_t)(n0 + sr) * K + sk;
  const u16* gB1 = BT + (size_t)(n0 + 64 + sr) * K + sk;
  u16* lA0 = &As[(size_t)(wave * 64) * 8];
  u16* lA1 = &As[(size_t)(256 + wave * 64) * 8];
  u16* lB0 = &Bs[(size_t)(wave * 64) * 8];
  u16* lB1 = &Bs[(size_t)(256 + wave * 64) * 8];
  for (int kk = 0; kk < K; kk += 32) {
    gl_lds16(gA0 + kk, lA0);
    gl_lds16(gA1 + kk, lA1);
    gl_lds16(gB0 + kk, lB0);
    gl_lds16(gB1 + kk, lB1);
    __syncthreads();
    bf16x8 af[4], bf[4];
#pragma unroll
    for (int t = 0; t < 4; t++) {
      af[t] = *(const bf16x8*)&As[(wr + t * 16 + ln) * 32 + qd * 8];
      bf[t] = *(const bf16x8*)&Bs[(wc + t * 16 + ln) * 32 + qd * 8];
    }
#pragma unroll
    for (int mt = 0; mt < 4; mt++)
#pragma unroll
      for (int nt = 0; nt < 4; nt++)
        acc[mt][nt] = __builtin_amdgcn_mfma_f32_16x16x32_bf16(af[mt], bf[nt], acc[mt][nt], 0, 0, 0);
    __syncthreads();
  }
  if (outT) {
#pragma unroll
    for (int nt = 0; nt < 4; nt++) {
      int col = n0 + wc + nt * 16 + ln;
      float bv = bias[col];
#pragma unroll
      for (int mt = 0; mt < 4; mt++) {
        u16 pk[4];
#pragma unroll
        for (int r = 0; r < 4; r++) pk[r] = f2b(acc[mt][nt][r] + bv);
        int row0 = m0 + wr + mt * 16 + qd * 4;
        *(uint2*)&outT[(size_t)col * M + row0] = *(uint2*)pk;
      }
    }
    return;
  }
#pragma unroll
  for (int nt = 0; nt < 4; nt++) {
    int col = n0 + wc + nt * 16 + ln;
    float bv = bias[col];
#pragma unroll
    for (int mt = 0; mt < 4; mt++) {
#pragma unroll
      for (int r = 0; r < 4; r++) {
        int row = m0 + wr + mt * 16 + qd * 4 + r;
        float v = acc[mt][nt][r] + bv;
        if (outF) outF[(size_t)row * N + col] = v;
        else      outB[(size_t)row * N + col] = f2b(v);
      }
    }
  }
}

// Register-q featurize of a 32-el chunk (e = 32*KT + 16*p .. +15) into dst (contiguous 16 u16).
template<int KT>
__device__ __forceinline__ void feat_row(const float* q16, int p, u16* dst) {
  u16 pk[16];
  if (KT == 0 && p == 0) {
    pk[0] = 0x3F80;  // 1.0 bf16
#pragma unroll
    for (int j = 1; j < 16; j++) pk[j] = f2b(0.5f * q16[j - 1]);
  } else if (KT == 0) {  // p==1: e=16..31
    pk[0] = f2b(0.5f * q16[15]);
    float wm = C2 * q16[0];
#pragma unroll
    for (int j = 1; j < 16; j++) pk[j] = f2b(wm * q16[j - 1]);
  } else {
    constexpr int c = 2 * KT;
    float wm = C2 * (p ? q16[c]     : q16[c - 1]);
    float w0 = C2 * (p ? q16[c - 1] : q16[c - 2]);
    pk[0] = f2b(w0 * q16[15]);
#pragma unroll
    for (int j = 1; j < 16; j++) pk[j] = f2b(wm * q16[j - 1]);
    if (KT == 8 && p) {  // e >= 273 -> 0
#pragma unroll
      for (int j = 1; j < 16; j++) pk[j] = 0;
    }
  }
  *(uint4*)dst = *(uint4*)pk;
  *(uint4*)(dst + 8) = *(uint4*)(pk + 8);
}

// Register-k featurize for chunk_sums: mt = MTB + 2p -> buffer (mt & 3), [el][t] layout
template<int MTB>
__device__ __forceinline__ void kfeat(const float* k16, int p, int t2, u16 (*kfT)[16][136]) {
  u16 pk[16];
  if (MTB == 0 && true) {
    if (p == 0) {  // mt 0
      pk[0] = 0x3F80;
#pragma unroll
      for (int j = 1; j < 16; j++) pk[j] = f2b(0.5f * k16[j - 1]);
    } else {       // mt 2
      float w0 = C2 * k16[0], wm = C2 * k16[1];
      pk[0] = f2b(w0 * k16[15]);
#pragma unroll
      for (int j = 1; j < 16; j++) pk[j] = f2b(wm * k16[j - 1]);
    }
  } else if (MTB == 1) {
    if (p == 0) {  // mt 1: e=16..31
      pk[0] = f2b(0.5f * k16[15]);
      float wm = C2 * k16[0];
#pragma unroll
      for (int j = 1; j < 16; j++) pk[j] = f2b(wm * k16[j - 1]);
    } else {       // mt 3
      float w0 = C2 * k16[1], wm = C2 * k16[2];
      pk[0] = f2b(w0 * k16[15]);
#pragma unroll
      for (int j = 1; j < 16; j++) pk[j] = f2b(wm * k16[j - 1]);
    }
  } else {
    float wm = C2 * (p ? k16[MTB + 1] : k16[MTB - 1]);
    float w0 = C2 * (p ? k16[MTB]     : k16[MTB - 2]);
    pk[0] = f2b(w0 * k16[15]);
#pragma unroll
    for (int j = 1; j < 16; j++) pk[j] = f2b(wm * k16[j - 1]);
  }
  int b = 2 * p + (MTB & 1);
#pragma unroll
  for (int el = 0; el < 16; el++) kfT[b][el][t2] = pk[el];
}

// Per (b,h,chunk of 128): ckvT[hd][e] = sum_t Kf[t][e]*V[t][hd] (bf16), ck[e] = colsum Kf (fp32)
__global__ __launch_bounds__(256) void chunk_sums(const float* __restrict__ qkw, const u16* __restrict__ vbT,
                                                  u16* __restrict__ ckvT, float* __restrict__ ck) {
  __shared__ float kl[CHK][20];
  __shared__ __align__(16) u16 kfT[4][16][136];
  const int tid = threadIdx.x;
  const int bh = blockIdx.x / NC, c = blockIdx.x % NC;
  const int b = bh >> 4, h = bh & 15;
  const int wave = tid >> 6, lane = tid & 63, qd = lane >> 4, ln = lane & 15;
  const int t2 = tid >> 1, p = tid & 1;
  const size_t rowbase = (size_t)(b * SEQ + c * CHK);
  float k16[16];
  {
    const float* kp = &qkw[(rowbase + t2) * QKS + 256 + h * FEAT];
    float4 v0 = *(const float4*)kp, v1 = *(const float4*)(kp + 4);
    float4 v2 = *(const float4*)(kp + 8), v3 = *(const float4*)(kp + 12);
    k16[0] = v0.x; k16[1] = v0.y; k16[2] = v0.z; k16[3] = v0.w;
    k16[4] = v1.x; k16[5] = v1.y; k16[6] = v1.z; k16[7] = v1.w;
    k16[8] = v2.x; k16[9] = v2.y; k16[10] = v2.z; k16[11] = v2.w;
    k16[12] = v3.x; k16[13] = v3.y; k16[14] = v3.z; k16[15] = v3.w;
    float4 h0, h1;
    if (p == 0) { h0 = v0; h1 = v1; } else { h0 = v2; h1 = v3; }
    *(float4*)&kl[t2][p * 8] = h0;
    *(float4*)&kl[t2][p * 8 + 4] = h1;
  }
  uint4 bVv[4][4];
#pragma unroll
  for (int kk2 = 0; kk2 < 4; kk2++)
#pragma unroll
    for (int nt = 0; nt < 4; nt++)
      bVv[kk2][nt] = *(const uint4*)&vbT[(size_t)(h * HD + nt * 16 + ln) * MROWS +
                                         rowbase + kk2 * 32 + qd * 8];
  const size_t obase = (size_t)(bh * NC + c) * HD;
  auto mstore = [&](int mt, int bufw) {
    f32x4 acc[4];
#pragma unroll
    for (int nt = 0; nt < 4; nt++) acc[nt] = (f32x4){0.f, 0.f, 0.f, 0.f};
#pragma unroll
    for (int kk2 = 0; kk2 < 4; kk2++) {
      bf16x8 a = *(const bf16x8*)&kfT[bufw][ln][kk2 * 32 + qd * 8];
#pragma unroll
      for (int nt = 0; nt < 4; nt++) {
        bf16x8 bb = *(const bf16x8*)&bVv[kk2][nt];
        acc[nt] = __builtin_amdgcn_mfma_f32_16x16x32_bf16(a, bb, acc[nt], 0, 0, 0);
      }
    }
#pragma unroll
    for (int nt = 0; nt < 4; nt++) {
      u16 pk[4];
#pragma unroll
      for (int r = 0; r < 4; r++) pk[r] = f2b(acc[nt][r]);
      *(uint2*)&ckvT[(obase + nt * 16 + ln) * EXPP + mt * 16 + qd * 4] = *(uint2*)pk;
    }
  };
  __syncthreads();
  kfeat<0>(k16, p, t2, kfT); kfeat<1>(k16, p, t2, kfT);
  __syncthreads();
  mstore(wave, wave);
  __syncthreads();
  kfeat<4>(k16, p, t2, kfT); kfeat<5>(k16, p, t2, kfT);
  __syncthreads();
  mstore(4 + wave, wave);
  __syncthreads();
  kfeat<8>(k16, p, t2, kfT); kfeat<9>(k16, p, t2, kfT);
  __syncthreads();
  mstore(8 + wave, wave);
  __syncthreads();
  kfeat<12>(k16, p, t2, kfT); kfeat<13>(k16, p, t2, kfT);
  __syncthreads();
  mstore(12 + wave, wave);
  __syncthreads();
  {  // mts 16,17 -> buffers 0,1
    u16 pk[16];
    if (p == 0) {  // mt 16: el0 i0=14; els1..15 i0=15
      float w0 = C2 * k16[14], wm = C2 * k16[15];
      pk[0] = f2b(w0 * k16[15]);
#pragma unroll
      for (int j = 1; j < 16; j++) pk[j] = f2b(wm * k16[j - 1]);
    } else {       // mt 17: only e=272 valid
      pk[0] = f2b(C2 * k16[15] * k16[15]);
#pragma unroll
      for (int j = 1; j < 16; j++) pk[j] = 0;
    }
#pragma unroll
    for (int el = 0; el < 16; el++) kfT[p][el][t2] = pk[el];
  }
  __syncthreads();
  if (wave < 2) mstore(16 + wave, wave);
  for (int e = tid; e < EXPP; e += 256) {
    float s = 0.f;
    if (e == 0) s = (float)CHK;
    else if (e < 17) { float t = 0.f; for (int tt = 0; tt < CHK; tt++) t += kl[tt][e - 1]; s = 0.5f * t; }
    else if (e < EXPD) {
      int u = e - 17, i0 = u >> 4, j0 = u & 15; float t = 0.f;
      for (int tt = 0; tt < CHK; tt++) t += kl[tt][i0] * kl[tt][j0];
      s = C2 * t;
    }
    ck[(size_t)(bh * NC + c) * EXPP + e] = s;
  }
}

// Exclusive prefix over chunks (in place, bf16) on ckvT; inclusive final -> out_kv.
__global__ __launch_bounds__(256) void kv_prefix(u16* __restrict__ ckvT, const float* __restrict__ kv0,
                                                 float* __restrict__ out_kv,
                                                 float* __restrict__ ck, const float* __restrict__ k0,
                                                 float* __restrict__ out_k) {
  const int tid = threadIdx.x;
  const int bh = blockIdx.x / 10, eg = blockIdx.x % 10;
  if (eg == 9) {
    for (int e = tid; e < EXPP; e += 256) {
      float S = (e < EXPD) ? k0[(size_t)bh * EXPD + e] : 0.f;
      for (int c = 0; c < NC; c++) {
        size_t idx = ((size_t)bh * NC + c) * EXPP + e;
        float v = ck[idx];
        ck[idx] = S;
        S += v;
      }
      if (e < EXPD) out_k[(size_t)bh * EXPD + e] = S;
    }
    return;
  }
  const int hd = tid >> 2;
  const int e0 = eg * 32 + (tid & 3) * 8;
  float S[8];
#pragma unroll
  for (int j = 0; j < 8; j++) {
    int e = e0 + j;
    S[j] = (e < EXPD) ? kv0[((size_t)bh * EXPD + e) * HD + hd] : 0.f;
  }
  u16* base = ckvT + ((size_t)bh * NC * HD + hd) * EXPP + e0;
  const size_t cstride = (size_t)HD * EXPP;
  uint4 v0 = *(const uint4*)base;
  uint4 v1 = *(const uint4*)(base + cstride);
  for (int c = 0; c < NC; c++) {
    uint4 vn = v1;
    if (c + 2 < NC) vn = *(const uint4*)(base + (size_t)(c + 2) * cstride);
    union { uint4 q; u16 s[8]; } pk;
#pragma unroll
    for (int j = 0; j < 8; j++) pk.s[j] = f2b(S[j]);
    *(uint4*)(base + (size_t)c * cstride) = pk.q;
    union { uint4 q; u16 s[8]; } vv; vv.q = v0;
#pragma unroll
    for (int j = 0; j < 8; j++) S[j] += b2f(vv.s[j]);
    v0 = v1; v1 = vn;
  }
#pragma unroll
  for (int j = 0; j < 8; j++) {
    int e = e0 + j;
    if (e < EXPD) out_kv[((size_t)bh * EXPD + e) * HD + hd] = S[j];
  }
}

// Per (b,h,chunk of 128): O = (Qf@S + mask_incl(poly(QK^T))@V) / den.
__global__ __launch_bounds__(256) void out_chunk(const float* __restrict__ qkw, const u16* __restrict__ vbT,
                                                 const u16* __restrict__ ckvT, const float* __restrict__ ck,
                                                 u16* __restrict__ ob) {
  __shared__ __align__(16) u16 pool[4 * CHK * 40];   // qlb | klb | qfs[2]; al overlays
  __shared__ float kstl[EXPP];
  __shared__ float denl[CHK];
  u16 (*qlb)[40] = (u16(*)[40])pool;
  u16 (*klb)[40] = (u16(*)[40])(pool + CHK * 40);
  u16 (*qfs)[CHK][40] = (u16(*)[CHK][40])(pool + 2 * CHK * 40);
  u16 (*al)[136] = (u16(*)[136])pool;                // 34816 B <= 40960 B
  const int tid = threadIdx.x;
  const int bh = blockIdx.x / NC, c = blockIdx.x % NC;
  const int b = bh >> 4, h = bh & 15;
  const int wave = tid >> 6, lane = tid & 63, qd = lane >> 4, ln = lane & 15;
  const int t2 = tid >> 1, p = tid & 1;
  const size_t rowbase = (size_t)(b * SEQ + c * CHK);
  float q16[16];
  {
    const float* qp = &qkw[(rowbase + t2) * QKS + h * FEAT];
    float4 v0 = *(const float4*)qp, v1 = *(const float4*)(qp + 4);
    float4 v2 = *(const float4*)(qp + 8), v3 = *(const float4*)(qp + 12);
    q16[0] = v0.x; q16[1] = v0.y; q16[2] = v0.z; q16[3] = v0.w;
    q16[4] = v1.x; q16[5] = v1.y; q16[6] = v1.z; q16[7] = v1.w;
    q16[8] = v2.x; q16[9] = v2.y; q16[10] = v2.z; q16[11] = v2.w;
    q16[12] = v3.x; q16[13] = v3.y; q16[14] = v3.z; q16[15] = v3.w;
    u16 qb[8];
#pragma unroll
    for (int j = 0; j < 8; j++) qb[j] = f2b(q16[p * 8 + j]);
    *(uint4*)&qlb[t2][p * 8] = *(uint4*)qb;
    *(uint4*)&qlb[t2][16 + p * 8] = (uint4){0u, 0u, 0u, 0u};
    const float* kp = &qkw[(rowbase + t2) * QKS + 256 + h * FEAT + p * 8];
    float4 k0v = *(const float4*)kp, k1v = *(const float4*)(kp + 4);
    u16 kb[8] = {f2b(k0v.x), f2b(k0v.y), f2b(k0v.z), f2b(k0v.w),
                 f2b(k1v.x), f2b(k1v.y), f2b(k1v.z), f2b(k1v.w)};
    *(uint4*)&klb[t2][p * 8] = *(uint4*)kb;
    *(uint4*)&klb[t2][16 + p * 8] = (uint4){0u, 0u, 0u, 0u};
  }
  const size_t cbase = (size_t)(bh * NC + c);
  for (int e = tid; e < EXPP; e += 256) kstl[e] = ck[cbase * EXPP + e];
  const u16* sptr = ckvT + (cbase * HD + wave * 16 + ln) * EXPP + qd * 8;
  uint4 bSv[9];
#pragma unroll
  for (int kt = 0; kt < 9; kt++) bSv[kt] = *(const uint4*)(sptr + kt * 32);
  uint4 bVv[4];
#pragma unroll
  for (int kk2 = 0; kk2 < 4; kk2++)
    bVv[kk2] = *(const uint4*)&vbT[(size_t)(h * HD + wave * 16 + ln) * MROWS +
                                   rowbase + kk2 * 32 + qd * 8];
  feat_row<0>(q16, p, &qfs[0][t2][p * 16]);
  __syncthreads();
  f32x4 accO[8];
#pragma unroll
  for (int mt = 0; mt < 8; mt++) accO[mt] = (f32x4){0.f, 0.f, 0.f, 0.f};
#define KSTEP(KT)                                                                          \
  {                                                                                        \
    if ((KT) < 8) feat_row<(KT) + 1>(q16, p, &qfs[((KT) + 1) & 1][t2][p * 16]);            \
    bf16x8 bS = *(const bf16x8*)&bSv[(KT)];                                                \
    _Pragma("unroll")                                                                      \
    for (int mt = 0; mt < 8; mt++) {                                                       \
      bf16x8 a = *(const bf16x8*)&qfs[(KT) & 1][mt * 16 + ln][qd * 8];                     \
      accO[mt] = __builtin_amdgcn_mfma_f32_16x16x32_bf16(a, bS, accO[mt], 0, 0, 0);        \
    }                                                                                      \
    __syncthreads();                                                                       \
  }
  KSTEP(0) KSTEP(1) KSTEP(2) KSTEP(3) KSTEP(4) KSTEP(5) KSTEP(6) KSTEP(7) KSTEP(8)
#undef KSTEP
  // scores: u = q.k for s-tiles {wave, wave+4}
  f32x4 accU[8][2];
#pragma unroll
  for (int st2 = 0; st2 < 2; st2++) {
    bf16x8 bU = *(const bf16x8*)&klb[(wave + st2 * 4) * 16 + ln][qd * 8];
#pragma unroll
    for (int mt = 0; mt < 8; mt++) {
      bf16x8 aU = *(const bf16x8*)&qlb[mt * 16 + ln][qd * 8];
      accU[mt][st2] = __builtin_amdgcn_mfma_f32_16x16x32_bf16(aU, bU, (f32x4){0.f, 0.f, 0.f, 0.f}, 0, 0, 0);
    }
  }
  __syncthreads();   // all qlb/klb reads done before al overwrites them
#pragma unroll
  for (int mt = 0; mt < 8; mt++)
#pragma unroll
    for (int st2 = 0; st2 < 2; st2++)
#pragma unroll
      for (int r = 0; r < 4; r++) {
        int t = mt * 16 + qd * 4 + r, s = (wave + st2 * 4) * 16 + ln;
        float u = accU[mt][st2][r];
        float sc = 1.f + 0.25f * u + 0.03125f * u * u;
        al[t][s] = f2b((s <= t) ? sc : 0.f);
      }
  __syncthreads();
#pragma unroll
  for (int kk2 = 0; kk2 < 4; kk2++) {
    bf16x8 bb = *(const bf16x8*)&bVv[kk2];
#pragma unroll
    for (int mt = 0; mt < 8; mt++) {
      bf16x8 a = *(const bf16x8*)&al[mt * 16 + ln][kk2 * 32 + qd * 8];
      accO[mt] = __builtin_amdgcn_mfma_f32_16x16x32_bf16(a, bb, accO[mt], 0, 0, 0);
    }
  }
  {
    float s = 0.f;
#pragma unroll
    for (int i2 = 0; i2 < 8; i2++) {
      int i = p * 8 + i2;
      float inner = 0.f;
#pragma unroll
      for (int j = 0; j < 16; j++) inner += q16[j] * kstl[17 + i * 16 + j];
      s += q16[i] * inner;
    }
    s *= C2;
    float s1 = 0.f;
#pragma unroll
    for (int j2 = 0; j2 < 8; j2++) s1 += q16[p * 8 + j2] * kstl[1 + p * 8 + j2];
    s += 0.5f * s1;
    if (p == 0) s += kstl[0] + 1e-6f;
    float da = 0.f;
#pragma unroll
    for (int sb = 0; sb < 8; sb++) {
      union { uint4 q; u16 hh[8]; } uu;
      uu.q = *(const uint4*)&al[t2][p * 64 + sb * 8];
#pragma unroll
      for (int j = 0; j < 8; j++) da += b2f(uu.hh[j]);
    }
    s += da;
    s += __shfl_xor(s, 1);
    if (p == 0) denl[t2] = s;
  }
  __syncthreads();
#pragma unroll
  for (int mt = 0; mt < 8; mt++)
#pragma unroll
    for (int r = 0; r < 4; r++) {
      int t = mt * 16 + qd * 4 + r;
      ob[(rowbase + t) * DM + h * HD + wave * 16 + ln] = f2b(accO[mt][r] / denl[t]);
    }
}

extern "C" void kernel_launch(void* const* d_in, const int* in_sizes, int n_in,
                              void* d_out, int out_size, void* d_ws, size_t ws_size,
                              hipStream_t stream) {
  (void)in_sizes; (void)n_in; (void)out_size;
  const float* x   = (const float*)d_in[0];
  const float* kv0 = (const float*)d_in[1];
  const float* k0  = (const float*)d_in[2];
  const float* bq  = (const float*)d_in[4];
  const float* bk  = (const float*)d_in[6];
  const float* bv  = (const float*)d_in[8];
  const float* bo  = (const float*)d_in[10];
  float* out = (float*)d_out;
  char* ws = (char*)d_ws;
  size_t off = 0;
  auto take = [&](size_t bytes) { char* p = ws + off; off += (bytes + 255) & ~(size_t)255; return p; };
  u16*   xb   = (u16*)  take((size_t)BATCH * SEQ * DM * 2);
  u16*   wqkT = (u16*)  take((size_t)QKS * DM * 2);
  u16*   wvT  = (u16*)  take((size_t)DM * DM * 2);
  u16*   woT  = (u16*)  take((size_t)DM * DM * 2);
  float* bqk  = (float*)take((size_t)QKS * 4);
  float* qkw  = (float*)take((size_t)BATCH * SEQ * QKS * 4);
  u16*   vbT  = (u16*)  take((size_t)BATCH * SEQ * DM * 2);
  u16*   ckvT = (u16*)  take((size_t)BH * NC * EXPP * HD * 2);
  float* ck   = (float*)take((size_t)BH * NC * EXPP * 4);
  u16*   ob   = (u16*)  take((size_t)BATCH * SEQ * DM * 2);
  if (off > ws_size) return;

  float* out_kv = out + (size_t)BATCH * SEQ * DM;
  float* out_k  = out_kv + (size_t)BH * EXPD * HD;

  prep<<<8192 + 2560 + 1, 256, 0, stream>>>(x, xb,
      (const float*)d_in[3], (const float*)d_in[5], (const float*)d_in[7], (const float*)d_in[9],
      wqkT, wvT, woT, bq, bk, bqk);

  gemm128<<<dim3(4, 64), 256, 0, stream>>>(xb, wqkT, bqk, MROWS, QKS, DM, qkw, nullptr, nullptr);
  gemm128<<<dim3(8, 64), 256, 0, stream>>>(xb, wvT,  bv,  MROWS, DM,  DM, nullptr, nullptr, vbT);

  chunk_sums<<<BH * NC, 256, 0, stream>>>(qkw, vbT, ckvT, ck);
  kv_prefix<<<BH * 10, 256, 0, stream>>>(ckvT, kv0, out_kv, ck, k0, out_k);
  out_chunk<<<BH * NC, 256, 0, stream>>>(qkw, vbT, ckvT, ck, ob);

  gemm128<<<dim3(8, 64), 256, 0, stream>>>(ob, woT, bo, MROWS, DM, DM, out, nullptr, nullptr);
}

// Round 9
// 291.201 us; speedup vs baseline: 1.0498x; 1.0498x over previous
//
#include <hip/hip_runtime.h>

typedef unsigned short u16;
typedef __attribute__((ext_vector_type(8))) short bf16x8;
typedef __attribute__((ext_vector_type(4))) float f32x4;

#define BATCH 4
#define SEQ   2048
#define DM    1024
#define HEADS 16
#define FEAT  16
#define HD    64
#define EXPD  273
#define EXPP  288   // padded to multiple of 32 for MFMA K
#define CHK   128
#define NC    16    // SEQ / CHK
#define BH    64    // BATCH*HEADS
#define QKS   512   // fused QK projection row stride
#define MROWS 8192  // BATCH*SEQ
#define C2    0.17677669529663687f  // 1/(sqrt(2)*sqrt(16))

__device__ __forceinline__ u16 f2b(float f) {
  union { float f; unsigned u; } v; v.f = f;
  unsigned u = v.u;
  return (u16)((u + 0x7fffu + ((u >> 16) & 1u)) >> 16);
}
__device__ __forceinline__ float b2f(u16 s) {
  union { unsigned u; float f; } v; v.u = ((unsigned)s) << 16; return v.f;
}

typedef const unsigned int __attribute__((address_space(1)))* gas1;
typedef unsigned int __attribute__((address_space(3)))* las3;
__device__ __forceinline__ void gl_lds16(const u16* g, u16* l) {
  __builtin_amdgcn_global_load_lds((gas1)(const void*)g, (las3)(void*)l, 16, 0, 0);
}

// Fused prep: x->bf16 (0..8191), weight cast-transposes (8192..10751), bias concat (10752..10757)
__global__ __launch_bounds__(256) void prep(const float* __restrict__ x, u16* __restrict__ xb,
                                            const float* __restrict__ Wq, const float* __restrict__ Wk,
                                            const float* __restrict__ Wv, const float* __restrict__ Wo,
                                            u16* __restrict__ wqkvT, u16* __restrict__ woT,
                                            const float* __restrict__ bq, const float* __restrict__ bk,
                                            const float* __restrict__ bv, float* __restrict__ bias_all) {
  __shared__ float tile[32][33];
  int id = blockIdx.x;
  if (id < 8192) {
    int i = id * 256 + threadIdx.x;
    float4 v = ((const float4*)x)[i];
    u16 r[4] = {f2b(v.x), f2b(v.y), f2b(v.z), f2b(v.w)};
    ((uint2*)xb)[i] = *(uint2*)r;
    return;
  }
  id -= 8192;
  if (id < 2560) {
    const float* src; u16* dst; int N, t;
    if (id < 256)       { src = Wq; dst = wqkvT;            N = 256;  t = id; }
    else if (id < 512)  { src = Wk; dst = wqkvT + 256 * DM; N = 256;  t = id - 256; }
    else if (id < 1536) { src = Wv; dst = wqkvT + 512 * DM; N = 1024; t = id - 512; }
    else                { src = Wo; dst = woT;              N = 1024; t = id - 1536; }
    int nt = N / 32;
    int n0 = (t % nt) * 32, k0 = (t / nt) * 32;
    int tx = threadIdx.x & 31, ty = threadIdx.x >> 5;
    for (int i = ty; i < 32; i += 8)
      tile[i][tx] = src[(size_t)(k0 + i) * N + n0 + tx];
    __syncthreads();
    for (int i = ty; i < 32; i += 8)
      dst[(size_t)(n0 + i) * DM + k0 + tx] = f2b(tile[tx][i]);
    return;
  }
  id -= 2560;
  int i = id * 256 + threadIdx.x;  // 0..1535
  float v;
  if (i < 256) v = bq[i];
  else if (i < 512) v = bk[i - 256];
  else v = bv[i - 512];
  bias_all[i] = v;
}

// Fused QKV projection: C = xb @ wqkvT^T + bias_all. N=1536.
// cols 0..511 -> qkw fp32 rm (stride 512); cols 512..1535 -> vbT bf16 transposed [col'][row].
__global__ __launch_bounds__(256) void gemmQKV(const u16* __restrict__ A, const u16* __restrict__ BT,
                                               const float* __restrict__ bias,
                                               float* __restrict__ qkw, u16* __restrict__ vbT) {
  __shared__ __align__(16) u16 As[128 * 32];
  __shared__ __align__(16) u16 Bs[128 * 32];
  const int tid = threadIdx.x;
  const int wave = tid >> 6, lane = tid & 63, qd = lane >> 4, ln = lane & 15;
  const int wr = (wave >> 1) * 64, wc = (wave & 1) * 64;
  const int m0 = blockIdx.y * 128, n0 = blockIdx.x * 128;
  const int K = DM;
  f32x4 acc[4][4];
#pragma unroll
  for (int i = 0; i < 4; i++)
#pragma unroll
    for (int j = 0; j < 4; j++) acc[i][j] = (f32x4){0.f, 0.f, 0.f, 0.f};
  const int sr = tid >> 2, sk = (tid & 3) * 8;
  const u16* gA0 = A + (size_t)(m0 + sr) * K + sk;
  const u16* gA1 = A + (size_t)(m0 + 64 + sr) * K + sk;
  const u16* gB0 = BT + (size_t)(n0 + sr) * K + sk;
  const u16* gB1 = BT + (size_t)(n0 + 64 + sr) * K + sk;
  u16* lA0 = &As[(size_t)(wave * 64) * 8];
  u16* lA1 = &As[(size_t)(256 + wave * 64) * 8];
  u16* lB0 = &Bs[(size_t)(wave * 64) * 8];
  u16* lB1 = &Bs[(size_t)(256 + wave * 64) * 8];
  for (int kk = 0; kk < K; kk += 32) {
    gl_lds16(gA0 + kk, lA0);
    gl_lds16(gA1 + kk, lA1);
    gl_lds16(gB0 + kk, lB0);
    gl_lds16(gB1 + kk, lB1);
    __syncthreads();
    bf16x8 af[4], bf[4];
#pragma unroll
    for (int t = 0; t < 4; t++) {
      af[t] = *(const bf16x8*)&As[(wr + t * 16 + ln) * 32 + qd * 8];
      bf[t] = *(const bf16x8*)&Bs[(wc + t * 16 + ln) * 32 + qd * 8];
    }
#pragma unroll
    for (int mt = 0; mt < 4; mt++)
#pragma unroll
      for (int nt = 0; nt < 4; nt++)
        acc[mt][nt] = __builtin_amdgcn_mfma_f32_16x16x32_bf16(af[mt], bf[nt], acc[mt][nt], 0, 0, 0);
    __syncthreads();
  }
  if (n0 < 512) {
#pragma unroll
    for (int nt = 0; nt < 4; nt++) {
      int col = n0 + wc + nt * 16 + ln;
      float bv = bias[col];
#pragma unroll
      for (int mt = 0; mt < 4; mt++)
#pragma unroll
        for (int r = 0; r < 4; r++) {
          int row = m0 + wr + mt * 16 + qd * 4 + r;
          qkw[(size_t)row * QKS + col] = acc[mt][nt][r] + bv;
        }
    }
  } else {
#pragma unroll
    for (int nt = 0; nt < 4; nt++) {
      int col = n0 + wc + nt * 16 + ln;
      float bv = bias[col];
      int vcol = col - 512;
#pragma unroll
      for (int mt = 0; mt < 4; mt++) {
        u16 pk[4];
#pragma unroll
        for (int r = 0; r < 4; r++) pk[r] = f2b(acc[mt][nt][r] + bv);
        int row0 = m0 + wr + mt * 16 + qd * 4;
        *(uint2*)&vbT[(size_t)vcol * MROWS + row0] = *(uint2*)pk;
      }
    }
  }
}

// C = A(MxK bf16 rm) @ BT^T + bias -> fp32 rm (used for the O projection)
__global__ __launch_bounds__(256) void gemm128(const u16* __restrict__ A, const u16* __restrict__ BT,
                                               const float* __restrict__ bias, int M, int N, int K,
                                               float* __restrict__ outF) {
  __shared__ __align__(16) u16 As[128 * 32];
  __shared__ __align__(16) u16 Bs[128 * 32];
  const int tid = threadIdx.x;
  const int wave = tid >> 6, lane = tid & 63, qd = lane >> 4, ln = lane & 15;
  const int wr = (wave >> 1) * 64, wc = (wave & 1) * 64;
  const int m0 = blockIdx.y * 128, n0 = blockIdx.x * 128;
  f32x4 acc[4][4];
#pragma unroll
  for (int i = 0; i < 4; i++)
#pragma unroll
    for (int j = 0; j < 4; j++) acc[i][j] = (f32x4){0.f, 0.f, 0.f, 0.f};
  const int sr = tid >> 2, sk = (tid & 3) * 8;
  const u16* gA0 = A + (size_t)(m0 + sr) * K + sk;
  const u16* gA1 = A + (size_t)(m0 + 64 + sr) * K + sk;
  const u16* gB0 = BT + (size_t)(n0 + sr) * K + sk;
  const u16* gB1 = BT + (size_t)(n0 + 64 + sr) * K + sk;
  u16* lA0 = &As[(size_t)(wave * 64) * 8];
  u16* lA1 = &As[(size_t)(256 + wave * 64) * 8];
  u16* lB0 = &Bs[(size_t)(wave * 64) * 8];
  u16* lB1 = &Bs[(size_t)(256 + wave * 64) * 8];
  for (int kk = 0; kk < K; kk += 32) {
    gl_lds16(gA0 + kk, lA0);
    gl_lds16(gA1 + kk, lA1);
    gl_lds16(gB0 + kk, lB0);
    gl_lds16(gB1 + kk, lB1);
    __syncthreads();
    bf16x8 af[4], bf[4];
#pragma unroll
    for (int t = 0; t < 4; t++) {
      af[t] = *(const bf16x8*)&As[(wr + t * 16 + ln) * 32 + qd * 8];
      bf[t] = *(const bf16x8*)&Bs[(wc + t * 16 + ln) * 32 + qd * 8];
    }
#pragma unroll
    for (int mt = 0; mt < 4; mt++)
#pragma unroll
      for (int nt = 0; nt < 4; nt++)
        acc[mt][nt] = __builtin_amdgcn_mfma_f32_16x16x32_bf16(af[mt], bf[nt], acc[mt][nt], 0, 0, 0);
    __syncthreads();
  }
#pragma unroll
  for (int nt = 0; nt < 4; nt++) {
    int col = n0 + wc + nt * 16 + ln;
    float bv = bias[col];
#pragma unroll
    for (int mt = 0; mt < 4; mt++)
#pragma unroll
      for (int r = 0; r < 4; r++) {
        int row = m0 + wr + mt * 16 + qd * 4 + r;
        outF[(size_t)row * N + col] = acc[mt][nt][r] + bv;
      }
  }
}

// Register-q featurize of a 32-el chunk (e = 32*KT + 16*p .. +15) into dst (contiguous 16 u16).
template<int KT>
__device__ __forceinline__ void feat_row(const float* q16, int p, u16* dst) {
  u16 pk[16];
  if (KT == 0 && p == 0) {
    pk[0] = 0x3F80;  // 1.0 bf16
#pragma unroll
    for (int j = 1; j < 16; j++) pk[j] = f2b(0.5f * q16[j - 1]);
  } else if (KT == 0) {  // p==1: e=16..31
    pk[0] = f2b(0.5f * q16[15]);
    float wm = C2 * q16[0];
#pragma unroll
    for (int j = 1; j < 16; j++) pk[j] = f2b(wm * q16[j - 1]);
  } else {
    constexpr int c = 2 * KT;
    float wm = C2 * (p ? q16[c]     : q16[c - 1]);
    float w0 = C2 * (p ? q16[c - 1] : q16[c - 2]);
    pk[0] = f2b(w0 * q16[15]);
#pragma unroll
    for (int j = 1; j < 16; j++) pk[j] = f2b(wm * q16[j - 1]);
    if (KT == 8 && p) {  // e >= 273 -> 0
#pragma unroll
      for (int j = 1; j < 16; j++) pk[j] = 0;
    }
  }
  *(uint4*)dst = *(uint4*)pk;
  *(uint4*)(dst + 8) = *(uint4*)(pk + 8);
}

// Register-k featurize for chunk_sums: mt = MTB + 2p -> buffer (mt & 3), [el][t] layout
template<int MTB>
__device__ __forceinline__ void kfeat(const float* k16, int p, int t2, u16 (*kfT)[16][136]) {
  u16 pk[16];
  if (MTB == 0) {
    if (p == 0) {
      pk[0] = 0x3F80;
#pragma unroll
      for (int j = 1; j < 16; j++) pk[j] = f2b(0.5f * k16[j - 1]);
    } else {
      float w0 = C2 * k16[0], wm = C2 * k16[1];
      pk[0] = f2b(w0 * k16[15]);
#pragma unroll
      for (int j = 1; j < 16; j++) pk[j] = f2b(wm * k16[j - 1]);
    }
  } else if (MTB == 1) {
    if (p == 0) {
      pk[0] = f2b(0.5f * k16[15]);
      float wm = C2 * k16[0];
#pragma unroll
      for (int j = 1; j < 16; j++) pk[j] = f2b(wm * k16[j - 1]);
    } else {
      float w0 = C2 * k16[1], wm = C2 * k16[2];
      pk[0] = f2b(w0 * k16[15]);
#pragma unroll
      for (int j = 1; j < 16; j++) pk[j] = f2b(wm * k16[j - 1]);
    }
  } else {
    float wm = C2 * (p ? k16[MTB + 1] : k16[MTB - 1]);
    float w0 = C2 * (p ? k16[MTB]     : k16[MTB - 2]);
    pk[0] = f2b(w0 * k16[15]);
#pragma unroll
    for (int j = 1; j < 16; j++) pk[j] = f2b(wm * k16[j - 1]);
  }
  int b = 2 * p + (MTB & 1);
#pragma unroll
  for (int el = 0; el < 16; el++) kfT[b][el][t2] = pk[el];
}

// Per (b,h,chunk of 128): ckvT[hd][e] = sum_t Kf[t][e]*V[t][hd] (bf16), ck[e] = colsum Kf (fp32)
__global__ __launch_bounds__(256) void chunk_sums(const float* __restrict__ qkw, const u16* __restrict__ vbT,
                                                  u16* __restrict__ ckvT, float* __restrict__ ck) {
  __shared__ float kl[CHK][20];
  __shared__ __align__(16) u16 kfT[4][16][136];
  const int tid = threadIdx.x;
  const int bh = blockIdx.x / NC, c = blockIdx.x % NC;
  const int b = bh >> 4, h = bh & 15;
  const int wave = tid >> 6, lane = tid & 63, qd = lane >> 4, ln = lane & 15;
  const int t2 = tid >> 1, p = tid & 1;
  const size_t rowbase = (size_t)(b * SEQ + c * CHK);
  float k16[16];
  {
    const float* kp = &qkw[(rowbase + t2) * QKS + 256 + h * FEAT];
    float4 v0 = *(const float4*)kp, v1 = *(const float4*)(kp + 4);
    float4 v2 = *(const float4*)(kp + 8), v3 = *(const float4*)(kp + 12);
    k16[0] = v0.x; k16[1] = v0.y; k16[2] = v0.z; k16[3] = v0.w;
    k16[4] = v1.x; k16[5] = v1.y; k16[6] = v1.z; k16[7] = v1.w;
    k16[8] = v2.x; k16[9] = v2.y; k16[10] = v2.z; k16[11] = v2.w;
    k16[12] = v3.x; k16[13] = v3.y; k16[14] = v3.z; k16[15] = v3.w;
    float4 h0, h1;
    if (p == 0) { h0 = v0; h1 = v1; } else { h0 = v2; h1 = v3; }
    *(float4*)&kl[t2][p * 8] = h0;
    *(float4*)&kl[t2][p * 8 + 4] = h1;
  }
  uint4 bVv[4][4];
#pragma unroll
  for (int kk2 = 0; kk2 < 4; kk2++)
#pragma unroll
    for (int nt = 0; nt < 4; nt++)
      bVv[kk2][nt] = *(const uint4*)&vbT[(size_t)(h * HD + nt * 16 + ln) * MROWS +
                                         rowbase + kk2 * 32 + qd * 8];
  const size_t obase = (size_t)(bh * NC + c) * HD;
  auto mstore = [&](int mt, int bufw) {
    f32x4 acc[4];
#pragma unroll
    for (int nt = 0; nt < 4; nt++) acc[nt] = (f32x4){0.f, 0.f, 0.f, 0.f};
#pragma unroll
    for (int kk2 = 0; kk2 < 4; kk2++) {
      bf16x8 a = *(const bf16x8*)&kfT[bufw][ln][kk2 * 32 + qd * 8];
#pragma unroll
      for (int nt = 0; nt < 4; nt++) {
        bf16x8 bb = *(const bf16x8*)&bVv[kk2][nt];
        acc[nt] = __builtin_amdgcn_mfma_f32_16x16x32_bf16(a, bb, acc[nt], 0, 0, 0);
      }
    }
#pragma unroll
    for (int nt = 0; nt < 4; nt++) {
      u16 pk[4];
#pragma unroll
      for (int r = 0; r < 4; r++) pk[r] = f2b(acc[nt][r]);
      *(uint2*)&ckvT[(obase + nt * 16 + ln) * EXPP + mt * 16 + qd * 4] = *(uint2*)pk;
    }
  };
  __syncthreads();
  kfeat<0>(k16, p, t2, kfT); kfeat<1>(k16, p, t2, kfT);
  __syncthreads();
  mstore(wave, wave);
  __syncthreads();
  kfeat<4>(k16, p, t2, kfT); kfeat<5>(k16, p, t2, kfT);
  __syncthreads();
  mstore(4 + wave, wave);
  __syncthreads();
  kfeat<8>(k16, p, t2, kfT); kfeat<9>(k16, p, t2, kfT);
  __syncthreads();
  mstore(8 + wave, wave);
  __syncthreads();
  kfeat<12>(k16, p, t2, kfT); kfeat<13>(k16, p, t2, kfT);
  __syncthreads();
  mstore(12 + wave, wave);
  __syncthreads();
  {  // mts 16,17 -> buffers 0,1
    u16 pk[16];
    if (p == 0) {
      float w0 = C2 * k16[14], wm = C2 * k16[15];
      pk[0] = f2b(w0 * k16[15]);
#pragma unroll
      for (int j = 1; j < 16; j++) pk[j] = f2b(wm * k16[j - 1]);
    } else {
      pk[0] = f2b(C2 * k16[15] * k16[15]);
#pragma unroll
      for (int j = 1; j < 16; j++) pk[j] = 0;
    }
#pragma unroll
    for (int el = 0; el < 16; el++) kfT[p][el][t2] = pk[el];
  }
  __syncthreads();
  if (wave < 2) mstore(16 + wave, wave);
  for (int e = tid; e < EXPP; e += 256) {
    float s = 0.f;
    if (e == 0) s = (float)CHK;
    else if (e < 17) { float t = 0.f; for (int tt = 0; tt < CHK; tt++) t += kl[tt][e - 1]; s = 0.5f * t; }
    else if (e < EXPD) {
      int u = e - 17, i0 = u >> 4, j0 = u & 15; float t = 0.f;
      for (int tt = 0; tt < CHK; tt++) t += kl[tt][i0] * kl[tt][j0];
      s = C2 * t;
    }
    ck[(size_t)(bh * NC + c) * EXPP + e] = s;
  }
}

// Exclusive prefix over chunks (in place, bf16) on ckvT; inclusive final -> out_kv.
__global__ __launch_bounds__(256) void kv_prefix(u16* __restrict__ ckvT, const float* __restrict__ kv0,
                                                 float* __restrict__ out_kv,
                                                 float* __restrict__ ck, const float* __restrict__ k0,
                                                 float* __restrict__ out_k) {
  const int tid = threadIdx.x;
  const int bh = blockIdx.x / 10, eg = blockIdx.x % 10;
  if (eg == 9) {
    for (int e = tid; e < EXPP; e += 256) {
      float S = (e < EXPD) ? k0[(size_t)bh * EXPD + e] : 0.f;
      for (int c = 0; c < NC; c++) {
        size_t idx = ((size_t)bh * NC + c) * EXPP + e;
        float v = ck[idx];
        ck[idx] = S;
        S += v;
      }
      if (e < EXPD) out_k[(size_t)bh * EXPD + e] = S;
    }
    return;
  }
  const int hd = tid >> 2;
  const int e0 = eg * 32 + (tid & 3) * 8;
  float S[8];
#pragma unroll
  for (int j = 0; j < 8; j++) {
    int e = e0 + j;
    S[j] = (e < EXPD) ? kv0[((size_t)bh * EXPD + e) * HD + hd] : 0.f;
  }
  u16* base = ckvT + ((size_t)bh * NC * HD + hd) * EXPP + e0;
  const size_t cstride = (size_t)HD * EXPP;
  uint4 v0 = *(const uint4*)base;
  uint4 v1 = *(const uint4*)(base + cstride);
  for (int c = 0; c < NC; c++) {
    uint4 vn = v1;
    if (c + 2 < NC) vn = *(const uint4*)(base + (size_t)(c + 2) * cstride);
    union { uint4 q; u16 s[8]; } pk;
#pragma unroll
    for (int j = 0; j < 8; j++) pk.s[j] = f2b(S[j]);
    *(uint4*)(base + (size_t)c * cstride) = pk.q;
    union { uint4 q; u16 s[8]; } vv; vv.q = v0;
#pragma unroll
    for (int j = 0; j < 8; j++) S[j] += b2f(vv.s[j]);
    v0 = v1; v1 = vn;
  }
#pragma unroll
  for (int j = 0; j < 8; j++) {
    int e = e0 + j;
    if (e < EXPD) out_kv[((size_t)bh * EXPD + e) * HD + hd] = S[j];
  }
}

// Per (b,h,chunk of 128): O = (Qf@S + mask_incl(poly(QK^T))@V) / den.
// All GEMMs in D[m=hd|s][n=t] orientation: A-frags from registers (bSv/bVv) or klb,
// B-frags = LDS rows (qfs/qlb/al). al written as packed uint2 from score C-layout.
__global__ __launch_bounds__(256) void out_chunk(const float* __restrict__ qkw, const u16* __restrict__ vbT,
                                                 const u16* __restrict__ ckvT, const float* __restrict__ ck,
                                                 u16* __restrict__ ob) {
  __shared__ __align__(16) u16 pool[18432];   // 36864 B
  __shared__ float kstl[EXPP];
  __shared__ float denl[CHK];
  u16 (*qlb)[40] = (u16(*)[40])pool;                 // 128x40, cols 16..31 zero
  u16 (*klb)[32] = (u16(*)[32])(pool + 5120);        // 128x32, cols 16..31 zero (NaN*0 guard)
  u16 (*qfs)[40] = (u16(*)[40])(pool + 9216);        // single-buffered Qf slab
  u16 (*alB)[72] = (u16(*)[72])pool;                 // scores s=64..127 (overlays qlb/klb, 9216 u16)
  u16 (*alA)[72] = (u16(*)[72])(pool + 9216);        // scores s=0..63   (overlays qfs)
  const int tid = threadIdx.x;
  const int bh = blockIdx.x / NC, c = blockIdx.x % NC;
  const int b = bh >> 4, h = bh & 15;
  const int wave = tid >> 6, lane = tid & 63, qd = lane >> 4, ln = lane & 15;
  const int t2 = tid >> 1, p = tid & 1;
  const size_t rowbase = (size_t)(b * SEQ + c * CHK);
  float q16[16];
  {
    const float* qp = &qkw[(rowbase + t2) * QKS + h * FEAT];
    float4 v0 = *(const float4*)qp, v1 = *(const float4*)(qp + 4);
    float4 v2 = *(const float4*)(qp + 8), v3 = *(const float4*)(qp + 12);
    q16[0] = v0.x; q16[1] = v0.y; q16[2] = v0.z; q16[3] = v0.w;
    q16[4] = v1.x; q16[5] = v1.y; q16[6] = v1.z; q16[7] = v1.w;
    q16[8] = v2.x; q16[9] = v2.y; q16[10] = v2.z; q16[11] = v2.w;
    q16[12] = v3.x; q16[13] = v3.y; q16[14] = v3.z; q16[15] = v3.w;
    u16 qb[8];
#pragma unroll
    for (int j = 0; j < 8; j++) qb[j] = f2b(q16[p * 8 + j]);
    *(uint4*)&qlb[t2][p * 8] = *(uint4*)qb;
    *(uint4*)&qlb[t2][16 + p * 8] = (uint4){0u, 0u, 0u, 0u};
    const float* kp = &qkw[(rowbase + t2) * QKS + 256 + h * FEAT + p * 8];
    float4 k0v = *(const float4*)kp, k1v = *(const float4*)(kp + 4);
    u16 kb[8] = {f2b(k0v.x), f2b(k0v.y), f2b(k0v.z), f2b(k0v.w),
                 f2b(k1v.x), f2b(k1v.y), f2b(k1v.z), f2b(k1v.w)};
    *(uint4*)&klb[t2][p * 8] = *(uint4*)kb;
    *(uint4*)&klb[t2][16 + p * 8] = (uint4){0u, 0u, 0u, 0u};
  }
  const size_t cbase = (size_t)(bh * NC + c);
  for (int e = tid; e < EXPP; e += 256) kstl[e] = ck[cbase * EXPP + e];
  const u16* sptr = ckvT + (cbase * HD + wave * 16 + ln) * EXPP + qd * 8;
  uint4 bSv[9];
#pragma unroll
  for (int kt = 0; kt < 9; kt++) bSv[kt] = *(const uint4*)(sptr + kt * 32);
  uint4 bVv[4];
#pragma unroll
  for (int kk2 = 0; kk2 < 4; kk2++)
    bVv[kk2] = *(const uint4*)&vbT[(size_t)(h * HD + wave * 16 + ln) * MROWS +
                                   rowbase + kk2 * 32 + qd * 8];
  feat_row<0>(q16, p, &qfs[t2][p * 16]);
  __syncthreads();
  f32x4 accO[8];
#pragma unroll
  for (int nt = 0; nt < 8; nt++) accO[nt] = (f32x4){0.f, 0.f, 0.f, 0.f};
#define KSTEP(KT)                                                                          \
  {                                                                                        \
    bf16x8 aS = *(const bf16x8*)&bSv[(KT)];                                                \
    _Pragma("unroll")                                                                      \
    for (int nt = 0; nt < 8; nt++) {                                                       \
      bf16x8 bQ = *(const bf16x8*)&qfs[nt * 16 + ln][qd * 8];                              \
      accO[nt] = __builtin_amdgcn_mfma_f32_16x16x32_bf16(aS, bQ, accO[nt], 0, 0, 0);       \
    }                                                                                      \
    __syncthreads();                                                                       \
    if ((KT) < 8) {                                                                        \
      feat_row<(KT) + 1>(q16, p, &qfs[t2][p * 16]);                                        \
      __syncthreads();                                                                     \
    }                                                                                      \
  }
  KSTEP(0) KSTEP(1) KSTEP(2) KSTEP(3) KSTEP(4) KSTEP(5) KSTEP(6) KSTEP(7) KSTEP(8)
#undef KSTEP
  // scores st2=0: s-tile = wave (s 0..63) -> alA (overlays qfs; safe after loop's last barrier)
  {
    f32x4 accU[8];
    bf16x8 aK = *(const bf16x8*)&klb[wave * 16 + ln][qd * 8];
#pragma unroll
    for (int nt = 0; nt < 8; nt++) {
      bf16x8 bQ = *(const bf16x8*)&qlb[nt * 16 + ln][qd * 8];
      accU[nt] = __builtin_amdgcn_mfma_f32_16x16x32_bf16(aK, bQ, (f32x4){0.f, 0.f, 0.f, 0.f}, 0, 0, 0);
    }
#pragma unroll
    for (int nt = 0; nt < 8; nt++) {
      int t = nt * 16 + ln, sb = wave * 16 + qd * 4;
      u16 pk[4];
#pragma unroll
      for (int r = 0; r < 4; r++) {
        float u = accU[nt][r];
        float sc = 1.f + 0.25f * u + 0.03125f * u * u;
        pk[r] = (sb + r <= t) ? f2b(sc) : (u16)0;
      }
      *(uint2*)&alA[t][sb] = *(uint2*)pk;
    }
  }
  // scores st2=1: s-tile = wave+4 (s 64..127) -> alB (overlays qlb/klb; barrier first)
  {
    f32x4 accU[8];
    bf16x8 aK = *(const bf16x8*)&klb[(wave + 4) * 16 + ln][qd * 8];
#pragma unroll
    for (int nt = 0; nt < 8; nt++) {
      bf16x8 bQ = *(const bf16x8*)&qlb[nt * 16 + ln][qd * 8];
      accU[nt] = __builtin_amdgcn_mfma_f32_16x16x32_bf16(aK, bQ, (f32x4){0.f, 0.f, 0.f, 0.f}, 0, 0, 0);
    }
    __syncthreads();   // all qlb/klb reads complete before alB overwrite
#pragma unroll
    for (int nt = 0; nt < 8; nt++) {
      int t = nt * 16 + ln, sbl = wave * 16 + qd * 4;
      u16 pk[4];
#pragma unroll
      for (int r = 0; r < 4; r++) {
        float u = accU[nt][r];
        float sc = 1.f + 0.25f * u + 0.03125f * u * u;
        pk[r] = (64 + sbl + r <= t) ? f2b(sc) : (u16)0;
      }
      *(uint2*)&alB[t][sbl] = *(uint2*)pk;
    }
  }
  __syncthreads();
  // A@V: A = V frags (registers), B = al rows
#pragma unroll
  for (int kk2 = 0; kk2 < 4; kk2++) {
    bf16x8 aV = *(const bf16x8*)&bVv[kk2];
#pragma unroll
    for (int nt = 0; nt < 8; nt++) {
      bf16x8 bA = (kk2 < 2) ? *(const bf16x8*)&alA[nt * 16 + ln][kk2 * 32 + qd * 8]
                            : *(const bf16x8*)&alB[nt * 16 + ln][(kk2 - 2) * 32 + qd * 8];
      accO[nt] = __builtin_amdgcn_mfma_f32_16x16x32_bf16(aV, bA, accO[nt], 0, 0, 0);
    }
  }
  // denominator: lane (t2,p): p=0 sums alA row, p=1 sums alB row; + kstl polynomial
  {
    float s = 0.f;
#pragma unroll
    for (int i2 = 0; i2 < 8; i2++) {
      int i = p * 8 + i2;
      float inner = 0.f;
#pragma unroll
      for (int j = 0; j < 16; j++) inner += q16[j] * kstl[17 + i * 16 + j];
      s += q16[i] * inner;
    }
    s *= C2;
    float s1 = 0.f;
#pragma unroll
    for (int j2 = 0; j2 < 8; j2++) s1 += q16[p * 8 + j2] * kstl[1 + p * 8 + j2];
    s += 0.5f * s1;
    if (p == 0) s += kstl[0] + 1e-6f;
    const u16* arow = p ? &alB[t2][0] : &alA[t2][0];
    float da = 0.f;
#pragma unroll
    for (int sb = 0; sb < 8; sb++) {
      union { uint4 q; u16 hh[8]; } uu;
      uu.q = *(const uint4*)(arow + sb * 8);
#pragma unroll
      for (int j = 0; j < 8; j++) da += b2f(uu.hh[j]);
    }
    s += da;
    s += __shfl_xor(s, 1);
    if (p == 0) denl[t2] = s;
  }
  __syncthreads();
  // output: lane holds hd = wave*16+qd*4+r, t = nt*16+ln -> packed uint2 along hd
#pragma unroll
  for (int nt = 0; nt < 8; nt++) {
    int t = nt * 16 + ln;
    float dn = denl[t];
    u16 pk[4];
#pragma unroll
    for (int r = 0; r < 4; r++) pk[r] = f2b(accO[nt][r] / dn);
    *(uint2*)&ob[(rowbase + t) * DM + h * HD + wave * 16 + qd * 4] = *(uint2*)pk;
  }
}

extern "C" void kernel_launch(void* const* d_in, const int* in_sizes, int n_in,
                              void* d_out, int out_size, void* d_ws, size_t ws_size,
                              hipStream_t stream) {
  (void)in_sizes; (void)n_in; (void)out_size;
  const float* x   = (const float*)d_in[0];
  const float* kv0 = (const float*)d_in[1];
  const float* k0  = (const float*)d_in[2];
  const float* bq  = (const float*)d_in[4];
  const float* bk  = (const float*)d_in[6];
  const float* bv  = (const float*)d_in[8];
  const float* bo  = (const float*)d_in[10];
  float* out = (float*)d_out;
  char* ws = (char*)d_ws;
  size_t off = 0;
  auto take = [&](size_t bytes) { char* p = ws + off; off += (bytes + 255) & ~(size_t)255; return p; };
  u16*   xb     = (u16*)  take((size_t)BATCH * SEQ * DM * 2);
  u16*   wqkvT  = (u16*)  take((size_t)1536 * DM * 2);
  u16*   woT    = (u16*)  take((size_t)DM * DM * 2);
  float* bias_a = (float*)take((size_t)1536 * 4);
  float* qkw    = (float*)take((size_t)BATCH * SEQ * QKS * 4);
  u16*   vbT    = (u16*)  take((size_t)BATCH * SEQ * DM * 2);
  u16*   ckvT   = (u16*)  take((size_t)BH * NC * EXPP * HD * 2);
  float* ck     = (float*)take((size_t)BH * NC * EXPP * 4);
  u16*   ob     = (u16*)  take((size_t)BATCH * SEQ * DM * 2);
  if (off > ws_size) return;

  float* out_kv = out + (size_t)BATCH * SEQ * DM;
  float* out_k  = out_kv + (size_t)BH * EXPD * HD;

  prep<<<8192 + 2560 + 6, 256, 0, stream>>>(x, xb,
      (const float*)d_in[3], (const float*)d_in[5], (const float*)d_in[7], (const float*)d_in[9],
      wqkvT, woT, bq, bk, bv, bias_a);

  gemmQKV<<<dim3(12, 64), 256, 0, stream>>>(xb, wqkvT, bias_a, qkw, vbT);

  chunk_sums<<<BH * NC, 256, 0, stream>>>(qkw, vbT, ckvT, ck);
  kv_prefix<<<BH * 10, 256, 0, stream>>>(ckvT, kv0, out_kv, ck, k0, out_k);
  out_chunk<<<BH * NC, 256, 0, stream>>>(qkw, vbT, ckvT, ck, ob);

  gemm128<<<dim3(8, 64), 256, 0, stream>>>(ob, woT, bo, MROWS, DM, DM, out);
}